// Round 1
// baseline (369.923 us; speedup 1.0000x reference)
//
#include <hip/hip_runtime.h>

// Polarization: pol[g] = sum_{i: batch[i]==g} (q[i] - mean(q)) * positions[i]
// positions: [N,3] f32, q: [N] f32, batch: [N] int32 (sorted), out: [1024,3] f32

#define NUM_GRAPHS 1024

__global__ void sum_q_kernel(const float* __restrict__ q, float* __restrict__ ws, int n4) {
    int tid = blockIdx.x * blockDim.x + threadIdx.x;
    int stride = gridDim.x * blockDim.x;
    const float4* q4 = (const float4*)q;
    float s = 0.f;
    for (int i = tid; i < n4; i += stride) {
        float4 v = q4[i];
        s += (v.x + v.y) + (v.z + v.w);
    }
    // wave64 butterfly
    for (int off = 32; off > 0; off >>= 1)
        s += __shfl_down(s, off, 64);
    __shared__ float smem[4];
    int lane = threadIdx.x & 63;
    int wave = threadIdx.x >> 6;
    if (lane == 0) smem[wave] = s;
    __syncthreads();
    if (threadIdx.x == 0) {
        float b = (smem[0] + smem[1]) + (smem[2] + smem[3]);
        atomicAdd(ws, b);
    }
}

__global__ void pol_kernel(const float* __restrict__ pos,
                           const float* __restrict__ q,
                           const int*   __restrict__ batch,
                           const float* __restrict__ ws,
                           float* __restrict__ out, int n) {
    const float mean = ws[0] * (1.0f / 8388608.0f);
    int tid = blockIdx.x * blockDim.x + threadIdx.x;
    int stride = gridDim.x * blockDim.x;
    int n4 = n >> 2;
    const float4* q4 = (const float4*)q;
    const int4*   b4 = (const int4*)batch;
    const float4* p4 = (const float4*)pos;

    for (int i = tid; i < n4; i += stride) {
        float4 qv = q4[i];
        int4   bv = b4[i];
        float4 p0 = p4[3 * i + 0];
        float4 p1 = p4[3 * i + 1];
        float4 p2 = p4[3 * i + 2];

        float qs[4] = {qv.x - mean, qv.y - mean, qv.z - mean, qv.w - mean};
        int  ids[4] = {bv.x, bv.y, bv.z, bv.w};
        float px[4] = {p0.x, p0.w, p1.z, p2.y};
        float py[4] = {p0.y, p1.x, p1.w, p2.z};
        float pz[4] = {p0.z, p1.y, p2.x, p2.w};

        int cur = ids[0];
        float sx = 0.f, sy = 0.f, sz = 0.f;
        #pragma unroll
        for (int j = 0; j < 4; ++j) {
            if (ids[j] != cur) {   // segment boundary inside this thread's 4 nodes (rare)
                atomicAdd(&out[cur * 3 + 0], sx);
                atomicAdd(&out[cur * 3 + 1], sy);
                atomicAdd(&out[cur * 3 + 2], sz);
                sx = sy = sz = 0.f;
                cur = ids[j];
            }
            sx = fmaf(qs[j], px[j], sx);
            sy = fmaf(qs[j], py[j], sy);
            sz = fmaf(qs[j], pz[j], sz);
        }

        // wave-level combine of residuals: common case all 64 lanes same graph
        int first = __shfl(cur, 0, 64);
        bool uniform = __all(cur == first);
        if (uniform) {
            for (int off = 32; off > 0; off >>= 1) {
                sx += __shfl_down(sx, off, 64);
                sy += __shfl_down(sy, off, 64);
                sz += __shfl_down(sz, off, 64);
            }
            if ((threadIdx.x & 63) == 0) {
                atomicAdd(&out[cur * 3 + 0], sx);
                atomicAdd(&out[cur * 3 + 1], sy);
                atomicAdd(&out[cur * 3 + 2], sz);
            }
        } else {   // wave straddles a graph boundary (<=1023 waves total)
            atomicAdd(&out[cur * 3 + 0], sx);
            atomicAdd(&out[cur * 3 + 1], sy);
            atomicAdd(&out[cur * 3 + 2], sz);
        }
    }
}

extern "C" void kernel_launch(void* const* d_in, const int* in_sizes, int n_in,
                              void* d_out, int out_size, void* d_ws, size_t ws_size,
                              hipStream_t stream) {
    const float* pos   = (const float*)d_in[0];
    const float* q     = (const float*)d_in[1];
    const int*   batch = (const int*)d_in[2];
    float* out = (float*)d_out;
    float* ws  = (float*)d_ws;
    int n = in_sizes[1];        // 8388608 nodes

    // harness poisons d_out / d_ws with 0xAA before every replay
    hipMemsetAsync(d_out, 0, (size_t)out_size * sizeof(float), stream);
    hipMemsetAsync(d_ws, 0, sizeof(float), stream);

    int n4 = n >> 2;
    sum_q_kernel<<<4096, 256, 0, stream>>>(q, ws, n4);

    // grid chosen so stride == n4 (2^21): exactly one iteration/thread,
    // every wave has a uniform trip count (shuffle-safe)
    pol_kernel<<<8192, 256, 0, stream>>>(pos, q, batch, ws, out, n);
}

// Round 3
// 222.753 us; speedup vs baseline: 1.6607x; 1.6607x over previous
//
#include <hip/hip_runtime.h>

// pol[g] = sum_{i in g} (q_i - mean(q)) * r_i = (sum_g q r) - mean * (sum_g r)
// Fast path (needs ~295 KB ws): one fused pass over pos/q/batch computes per-block
// {qsum, base_id, slot[4][6]} records with NO global atomics; tiny mean + finalize
// kernels combine records into out with plain stores. Fallback path = round-1
// atomic version (known correct) if ws_size is too small.

#define N_NODES         8388608
#define NUM_GRAPHS      1024
#define BLK             256
#define NODES_PER_BLOCK 4096
#define NBLOCKS         (N_NODES / NODES_PER_BLOCK)     // 2048
#define CHUNK_NODES     1024
#define NCHUNK          (NODES_PER_BLOCK / CHUNK_NODES) // 4
#define CHUNK_F4        (CHUNK_NODES * 3 / 4)           // 768
#define PAD4(u)         ((u) + ((u) >> 3))
#define LDS_F4          (CHUNK_F4 + (CHUNK_F4 >> 3))    // 864
#define NSLOT           4

// ws layout (float offsets)
#define IBASE_OFF       16                               // int ibase[NBLOCKS]
#define REC_OFF         2064                             // rec[NBLOCKS][32]: [0]=qsum, [8..31]=slots
#define REC_STRIDE      32
#define EXTRA_OFF       (REC_OFF + NBLOCKS * REC_STRIDE) // 67600: extra[NUM_GRAPHS][6]
#define WS_FLOATS       (EXTRA_OFF + NUM_GRAPHS * 6)     // 73744 floats = 294976 B

__global__ __launch_bounds__(BLK) void pol_main(const float4* __restrict__ p4,
                                                const float4* __restrict__ q4,
                                                const int4*   __restrict__ b4,
                                                const int*    __restrict__ batch,
                                                float* __restrict__ ws) {
    __shared__ float4 spos[LDS_F4];
    __shared__ float  sslot[NSLOT * 6];
    __shared__ float  sqsum;

    const int t = threadIdx.x;
    const int b = blockIdx.x;
    float* extra = ws + EXTRA_OFF;

    if (t == 0) sqsum = 0.f;
    if (t < NSLOT * 6) sslot[t] = 0.f;
    const int base = batch[b * NODES_PER_BLOCK];   // uniform load, no LDS needed

    int idA = -1, idB = -1;
    float aqx = 0, aqy = 0, aqz = 0, arx = 0, ary = 0, arz = 0;
    float bqx = 0, bqy = 0, bqz = 0, brx = 0, bry = 0, brz = 0;
    float qsum = 0.f;

    const int blk_f4 = b * (NODES_PER_BLOCK * 3 / 4);
    const int blk_v4 = b * (NODES_PER_BLOCK / 4);

    for (int c = 0; c < NCHUNK; ++c) {
        #pragma unroll
        for (int k = 0; k < 3; ++k) {
            int u = t + BLK * k;
            spos[PAD4(u)] = p4[blk_f4 + c * CHUNK_F4 + u];  // coalesced global read
        }
        __syncthreads();

        int vi = blk_v4 + c * (CHUNK_NODES / 4) + t;
        float4 qv = q4[vi];
        int4   bv = b4[vi];
        int u0 = 3 * t;
        float4 p0 = spos[PAD4(u0)];
        float4 p1 = spos[PAD4(u0 + 1)];
        float4 p2 = spos[PAD4(u0 + 2)];

        float qs[4] = {qv.x, qv.y, qv.z, qv.w};
        int   ids[4] = {bv.x, bv.y, bv.z, bv.w};
        float px[4] = {p0.x, p0.w, p1.z, p2.y};
        float py[4] = {p0.y, p1.x, p1.w, p2.z};
        float pz[4] = {p0.z, p1.y, p2.x, p2.w};

        #pragma unroll
        for (int j = 0; j < 4; ++j) {
            float qj = qs[j];
            int   id = ids[j];
            qsum += qj;
            if (id == idA) {
                aqx = fmaf(qj, px[j], aqx); aqy = fmaf(qj, py[j], aqy); aqz = fmaf(qj, pz[j], aqz);
                arx += px[j]; ary += py[j]; arz += pz[j];
            } else if (id == idB) {
                bqx = fmaf(qj, px[j], bqx); bqy = fmaf(qj, py[j], bqy); bqz = fmaf(qj, pz[j], bqz);
                brx += px[j]; bry += py[j]; brz += pz[j];
            } else if (idA < 0) {
                idA = id;
                aqx = qj * px[j]; aqy = qj * py[j]; aqz = qj * pz[j];
                arx = px[j]; ary = py[j]; arz = pz[j];
            } else if (idB < 0) {
                idB = id;
                bqx = qj * px[j]; bqy = qj * py[j]; bqz = qj * pz[j];
                brx = px[j]; bry = py[j]; brz = pz[j];
            } else {  // 3rd id per thread: impossible for this input; correct fallback
                atomicAdd(&extra[idA * 6 + 0], aqx); atomicAdd(&extra[idA * 6 + 1], aqy);
                atomicAdd(&extra[idA * 6 + 2], aqz); atomicAdd(&extra[idA * 6 + 3], arx);
                atomicAdd(&extra[idA * 6 + 4], ary); atomicAdd(&extra[idA * 6 + 5], arz);
                idA = id;
                aqx = qj * px[j]; aqy = qj * py[j]; aqz = qj * pz[j];
                arx = px[j]; ary = py[j]; arz = pz[j];
            }
        }
        __syncthreads();
    }

    // block qsum: proven wave butterfly + one LDS atomic per wave
    #pragma unroll
    for (int off = 32; off > 0; off >>= 1) qsum += __shfl_down(qsum, off, 64);
    if ((t & 63) == 0) atomicAdd(&sqsum, qsum);

    // per-thread flush: LDS atomics only (no cross-lane logic)
    {
        int s = idA - base;                      // idA always set; s >= 0 (sorted)
        if (s < NSLOT) {
            atomicAdd(&sslot[s * 6 + 0], aqx); atomicAdd(&sslot[s * 6 + 1], aqy);
            atomicAdd(&sslot[s * 6 + 2], aqz); atomicAdd(&sslot[s * 6 + 3], arx);
            atomicAdd(&sslot[s * 6 + 4], ary); atomicAdd(&sslot[s * 6 + 5], arz);
        } else {
            atomicAdd(&extra[idA * 6 + 0], aqx); atomicAdd(&extra[idA * 6 + 1], aqy);
            atomicAdd(&extra[idA * 6 + 2], aqz); atomicAdd(&extra[idA * 6 + 3], arx);
            atomicAdd(&extra[idA * 6 + 4], ary); atomicAdd(&extra[idA * 6 + 5], arz);
        }
    }
    if (idB >= 0) {
        int s = idB - base;
        if (s < NSLOT) {
            atomicAdd(&sslot[s * 6 + 0], bqx); atomicAdd(&sslot[s * 6 + 1], bqy);
            atomicAdd(&sslot[s * 6 + 2], bqz); atomicAdd(&sslot[s * 6 + 3], brx);
            atomicAdd(&sslot[s * 6 + 4], bry); atomicAdd(&sslot[s * 6 + 5], brz);
        } else {
            atomicAdd(&extra[idB * 6 + 0], bqx); atomicAdd(&extra[idB * 6 + 1], bqy);
            atomicAdd(&extra[idB * 6 + 2], bqz); atomicAdd(&extra[idB * 6 + 3], brx);
            atomicAdd(&extra[idB * 6 + 4], bry); atomicAdd(&extra[idB * 6 + 5], brz);
        }
    }
    __syncthreads();

    float* rec = ws + REC_OFF + (size_t)b * REC_STRIDE;
    if (t == 0) {
        rec[0] = sqsum;
        ((int*)(ws + IBASE_OFF))[b] = base;
    }
    if (t < NSLOT * 6) rec[8 + t] = sslot[t];
}

__global__ __launch_bounds__(BLK) void mean_kernel(float* __restrict__ ws) {
    __shared__ float sm[4];
    float s = 0.f;
    for (int i = threadIdx.x; i < NBLOCKS; i += BLK) s += ws[REC_OFF + (size_t)i * REC_STRIDE];
    #pragma unroll
    for (int off = 32; off > 0; off >>= 1) s += __shfl_down(s, off, 64);
    int lane = threadIdx.x & 63, wave = threadIdx.x >> 6;
    if (lane == 0) sm[wave] = s;
    __syncthreads();
    if (threadIdx.x == 0) ws[0] = ((sm[0] + sm[1]) + (sm[2] + sm[3])) * (1.0f / (float)N_NODES);
}

__global__ __launch_bounds__(BLK) void finalize_kernel(const float* __restrict__ ws,
                                                       float* __restrict__ out) {
    int g = blockIdx.x * BLK + threadIdx.x;
    if (g >= NUM_GRAPHS) return;
    const float mean = ws[0];
    const int* ibase = (const int*)(ws + IBASE_OFF);
    const float* extra = ws + EXTRA_OFF;

    float qx = extra[g * 6 + 0], qy = extra[g * 6 + 1], qz = extra[g * 6 + 2];
    float rx = extra[g * 6 + 3], ry = extra[g * 6 + 4], rz = extra[g * 6 + 5];

    // last block b with ibase[b] <= g
    int lo = 0, hi = NBLOCKS - 1, B = -1;
    while (lo <= hi) {
        int mid = (lo + hi) >> 1;
        if (ibase[mid] <= g) { B = mid; lo = mid + 1; } else hi = mid - 1;
    }
    // walk left; block b's slot (g - ibase[b]) holds id g's partial (zero if absent)
    for (int b = B; b >= 0; --b) {
        int s = g - ibase[b];
        if (s >= NSLOT) break;   // earlier blocks: any id-g spill went to extra[]
        const float* sl = ws + REC_OFF + (size_t)b * REC_STRIDE + 8 + s * 6;
        qx += sl[0]; qy += sl[1]; qz += sl[2];
        rx += sl[3]; ry += sl[4]; rz += sl[5];
    }
    out[g * 3 + 0] = fmaf(-mean, rx, qx);
    out[g * 3 + 1] = fmaf(-mean, ry, qy);
    out[g * 3 + 2] = fmaf(-mean, rz, qz);
}

// ---------------- fallback path (round-1 code, known correct) ----------------

__global__ void sum_q_kernel(const float* __restrict__ q, float* __restrict__ ws, int n4) {
    int tid = blockIdx.x * blockDim.x + threadIdx.x;
    int stride = gridDim.x * blockDim.x;
    const float4* q4 = (const float4*)q;
    float s = 0.f;
    for (int i = tid; i < n4; i += stride) {
        float4 v = q4[i];
        s += (v.x + v.y) + (v.z + v.w);
    }
    for (int off = 32; off > 0; off >>= 1) s += __shfl_down(s, off, 64);
    __shared__ float smem[4];
    int lane = threadIdx.x & 63, wave = threadIdx.x >> 6;
    if (lane == 0) smem[wave] = s;
    __syncthreads();
    if (threadIdx.x == 0) atomicAdd(ws, (smem[0] + smem[1]) + (smem[2] + smem[3]));
}

__global__ void pol_atomic_kernel(const float* __restrict__ pos,
                                  const float* __restrict__ q,
                                  const int*   __restrict__ batch,
                                  const float* __restrict__ ws,
                                  float* __restrict__ out, int n) {
    const float mean = ws[0] * (1.0f / (float)N_NODES);
    int tid = blockIdx.x * blockDim.x + threadIdx.x;
    int stride = gridDim.x * blockDim.x;
    int n4 = n >> 2;
    const float4* q4 = (const float4*)q;
    const int4*   b4 = (const int4*)batch;
    const float4* p4 = (const float4*)pos;

    for (int i = tid; i < n4; i += stride) {
        float4 qv = q4[i];
        int4   bv = b4[i];
        float4 p0 = p4[3 * i + 0];
        float4 p1 = p4[3 * i + 1];
        float4 p2 = p4[3 * i + 2];
        float qs[4] = {qv.x - mean, qv.y - mean, qv.z - mean, qv.w - mean};
        int  ids[4] = {bv.x, bv.y, bv.z, bv.w};
        float px[4] = {p0.x, p0.w, p1.z, p2.y};
        float py[4] = {p0.y, p1.x, p1.w, p2.z};
        float pz[4] = {p0.z, p1.y, p2.x, p2.w};
        int cur = ids[0];
        float sx = 0.f, sy = 0.f, sz = 0.f;
        #pragma unroll
        for (int j = 0; j < 4; ++j) {
            if (ids[j] != cur) {
                atomicAdd(&out[cur * 3 + 0], sx);
                atomicAdd(&out[cur * 3 + 1], sy);
                atomicAdd(&out[cur * 3 + 2], sz);
                sx = sy = sz = 0.f;
                cur = ids[j];
            }
            sx = fmaf(qs[j], px[j], sx);
            sy = fmaf(qs[j], py[j], sy);
            sz = fmaf(qs[j], pz[j], sz);
        }
        int first = __shfl(cur, 0, 64);
        bool uniform = __all(cur == first);
        if (uniform) {
            for (int off = 32; off > 0; off >>= 1) {
                sx += __shfl_down(sx, off, 64);
                sy += __shfl_down(sy, off, 64);
                sz += __shfl_down(sz, off, 64);
            }
            if ((threadIdx.x & 63) == 0) {
                atomicAdd(&out[cur * 3 + 0], sx);
                atomicAdd(&out[cur * 3 + 1], sy);
                atomicAdd(&out[cur * 3 + 2], sz);
            }
        } else {
            atomicAdd(&out[cur * 3 + 0], sx);
            atomicAdd(&out[cur * 3 + 1], sy);
            atomicAdd(&out[cur * 3 + 2], sz);
        }
    }
}

extern "C" void kernel_launch(void* const* d_in, const int* in_sizes, int n_in,
                              void* d_out, int out_size, void* d_ws, size_t ws_size,
                              hipStream_t stream) {
    const float* pos   = (const float*)d_in[0];
    const float* q     = (const float*)d_in[1];
    const int*   batch = (const int*)d_in[2];
    float* out = (float*)d_out;
    float* ws  = (float*)d_ws;
    int n = in_sizes[1];

    if (ws_size >= (size_t)WS_FLOATS * sizeof(float)) {
        // fast path: no global atomics, no out-memset (finalize writes every element)
        hipMemsetAsync(ws + EXTRA_OFF, 0, (size_t)NUM_GRAPHS * 6 * sizeof(float), stream);
        pol_main<<<NBLOCKS, BLK, 0, stream>>>((const float4*)pos, (const float4*)q,
                                              (const int4*)batch, batch, ws);
        mean_kernel<<<1, BLK, 0, stream>>>(ws);
        finalize_kernel<<<NUM_GRAPHS / BLK, BLK, 0, stream>>>(ws, out);
    } else {
        // fallback: round-1 structure (correct, slower)
        hipMemsetAsync(d_out, 0, (size_t)out_size * sizeof(float), stream);
        hipMemsetAsync(d_ws, 0, sizeof(float), stream);
        sum_q_kernel<<<4096, BLK, 0, stream>>>(q, ws, n >> 2);
        pol_atomic_kernel<<<8192, BLK, 0, stream>>>(pos, q, batch, ws, out, n);
    }
}

// Round 4
// 210.251 us; speedup vs baseline: 1.7594x; 1.0595x over previous
//
#include <hip/hip_runtime.h>

// pol[g] = sum_{i in g} (q_i - mean(q)) * r_i = (sum_g q r) - mean * (sum_g r)
// pol_main: 2048 blocks x 256 thr, 16 nodes/thread, NO in-loop barriers, direct
// global loads (max MLP). Per-thread (idA,idB) segment state; wave-butterfly
// flush to per-block LDS slots; plain-store records to ws.
// finalize: single 1024-thread block computes mean from block qsums, then
// gathers each graph's partials via binary search over sorted block base ids.

#define N_NODES         8388608
#define NUM_GRAPHS      1024
#define BLK             256
#define NODES_PER_BLOCK 4096
#define NBLOCKS         (N_NODES / NODES_PER_BLOCK)     // 2048
#define ITER            4                                // ITER*BLK*4 == NODES_PER_BLOCK
#define NSLOT           4

// ws layout (float offsets)
#define IBASE_OFF       16                               // int ibase[NBLOCKS]
#define REC_OFF         2064                             // rec[NBLOCKS][32]: [0]=qsum, [8..31]=slots
#define REC_STRIDE      32
#define EXTRA_OFF       (REC_OFF + NBLOCKS * REC_STRIDE) // 67600
#define WS_FLOATS       (EXTRA_OFF + NUM_GRAPHS * 6)     // 73744 floats = 294976 B

__device__ __forceinline__ void flush_seg(int id, int base,
                                          float qx, float qy, float qz,
                                          float rx, float ry, float rz,
                                          float* sslot, float* extra) {
    int s = id - base;   // sorted batch => s >= 0
    if (s < NSLOT) {
        atomicAdd(&sslot[s * 6 + 0], qx); atomicAdd(&sslot[s * 6 + 1], qy);
        atomicAdd(&sslot[s * 6 + 2], qz); atomicAdd(&sslot[s * 6 + 3], rx);
        atomicAdd(&sslot[s * 6 + 4], ry); atomicAdd(&sslot[s * 6 + 5], rz);
    } else {  // impossible for this input; correct fallback
        atomicAdd(&extra[id * 6 + 0], qx); atomicAdd(&extra[id * 6 + 1], qy);
        atomicAdd(&extra[id * 6 + 2], qz); atomicAdd(&extra[id * 6 + 3], rx);
        atomicAdd(&extra[id * 6 + 4], ry); atomicAdd(&extra[id * 6 + 5], rz);
    }
}

__global__ __launch_bounds__(BLK) void pol_main(const float4* __restrict__ p4,
                                                const float4* __restrict__ q4,
                                                const int4*   __restrict__ b4,
                                                const int*    __restrict__ batch,
                                                float* __restrict__ ws) {
    __shared__ float sslot[NSLOT * 6];
    __shared__ float sqsum;

    const int t = threadIdx.x;
    const int b = blockIdx.x;
    float* extra = ws + EXTRA_OFF;

    if (t == 0) sqsum = 0.f;
    if (t < NSLOT * 6) sslot[t] = 0.f;
    const int base = batch[b * NODES_PER_BLOCK];  // wave-uniform broadcast load
    __syncthreads();   // protect inits from a fast wave's flush (waves can skew)

    int idA = -1, idB = -1;
    float aqx = 0, aqy = 0, aqz = 0, arx = 0, ary = 0, arz = 0;
    float bqx = 0, bqy = 0, bqz = 0, brx = 0, bry = 0, brz = 0;
    float qsum = 0.f;

    const int blk_v4 = b * (NODES_PER_BLOCK / 4);

    #pragma unroll
    for (int j = 0; j < ITER; ++j) {
        int vi = blk_v4 + j * BLK + t;        // coalesced q/batch; pos spans full lines/wave
        float4 qv = q4[vi];
        int4   bv = b4[vi];
        float4 p0 = p4[3 * vi + 0];
        float4 p1 = p4[3 * vi + 1];
        float4 p2 = p4[3 * vi + 2];

        float qs[4] = {qv.x, qv.y, qv.z, qv.w};
        int   ids[4] = {bv.x, bv.y, bv.z, bv.w};
        float px[4] = {p0.x, p0.w, p1.z, p2.y};
        float py[4] = {p0.y, p1.x, p1.w, p2.z};
        float pz[4] = {p0.z, p1.y, p2.x, p2.w};

        #pragma unroll
        for (int k = 0; k < 4; ++k) {
            float qj = qs[k];
            int   id = ids[k];
            qsum += qj;
            if (id == idA) {
                aqx = fmaf(qj, px[k], aqx); aqy = fmaf(qj, py[k], aqy); aqz = fmaf(qj, pz[k], aqz);
                arx += px[k]; ary += py[k]; arz += pz[k];
            } else if (id == idB) {
                bqx = fmaf(qj, px[k], bqx); bqy = fmaf(qj, py[k], bqy); bqz = fmaf(qj, pz[k], bqz);
                brx += px[k]; bry += py[k]; brz += pz[k];
            } else if (idA < 0) {
                idA = id;
                aqx = qj * px[k]; aqy = qj * py[k]; aqz = qj * pz[k];
                arx = px[k]; ary = py[k]; arz = pz[k];
            } else if (idB < 0) {
                idB = id;
                bqx = qj * px[k]; bqy = qj * py[k]; bqz = qj * pz[k];
                brx = px[k]; bry = py[k]; brz = pz[k];
            } else {  // 3rd distinct id in one thread: impossible here, safe fallback
                atomicAdd(&extra[idA * 6 + 0], aqx); atomicAdd(&extra[idA * 6 + 1], aqy);
                atomicAdd(&extra[idA * 6 + 2], aqz); atomicAdd(&extra[idA * 6 + 3], arx);
                atomicAdd(&extra[idA * 6 + 4], ary); atomicAdd(&extra[idA * 6 + 5], arz);
                idA = id;
                aqx = qj * px[k]; aqy = qj * py[k]; aqz = qj * pz[k];
                arx = px[k]; ary = py[k]; arz = pz[k];
            }
        }
    }

    // block qsum: wave butterfly + one LDS atomic per wave
    #pragma unroll
    for (int off = 32; off > 0; off >>= 1) qsum += __shfl_down(qsum, off, 64);
    if ((t & 63) == 0) atomicAdd(&sqsum, qsum);

    // segment A flush: every lane has idA set
    bool uniA = __all(idA == __shfl(idA, 0, 64));
    if (uniA) {
        #pragma unroll
        for (int off = 32; off > 0; off >>= 1) {
            aqx += __shfl_down(aqx, off, 64); aqy += __shfl_down(aqy, off, 64);
            aqz += __shfl_down(aqz, off, 64); arx += __shfl_down(arx, off, 64);
            ary += __shfl_down(ary, off, 64); arz += __shfl_down(arz, off, 64);
        }
        if ((t & 63) == 0) flush_seg(idA, base, aqx, aqy, aqz, arx, ary, arz, sslot, extra);
    } else {  // boundary wave (<=1023 in whole grid): per-lane flush
        flush_seg(idA, base, aqx, aqy, aqz, arx, ary, arz, sslot, extra);
    }

    // segment B flush
    unsigned long long mB = __ballot(idB >= 0);
    if (mB) {
        bool allB  = (mB == ~0ull);
        int  firstB = __shfl(idB, 0, 64);
        bool uniB  = allB && __all(idB == firstB);
        if (uniB) {
            #pragma unroll
            for (int off = 32; off > 0; off >>= 1) {
                bqx += __shfl_down(bqx, off, 64); bqy += __shfl_down(bqy, off, 64);
                bqz += __shfl_down(bqz, off, 64); brx += __shfl_down(brx, off, 64);
                bry += __shfl_down(bry, off, 64); brz += __shfl_down(brz, off, 64);
            }
            if ((t & 63) == 0) flush_seg(idB, base, bqx, bqy, bqz, brx, bry, brz, sslot, extra);
        } else if (idB >= 0) {
            flush_seg(idB, base, bqx, bqy, bqz, brx, bry, brz, sslot, extra);
        }
    }
    __syncthreads();

    float* rec = ws + REC_OFF + (size_t)b * REC_STRIDE;
    if (t == 0) {
        rec[0] = sqsum;
        ((int*)(ws + IBASE_OFF))[b] = base;
    }
    if (t < NSLOT * 6) rec[8 + t] = sslot[t];
}

// Single block, 1024 threads: phase 1 computes mean from the 2048 block qsums,
// phase 2 gathers each graph's partials (round-3 proven logic) with plain stores.
__global__ __launch_bounds__(1024) void finalize_kernel(const float* __restrict__ ws,
                                                        float* __restrict__ out) {
    __shared__ float sm[16];
    __shared__ float smean;
    const int t = threadIdx.x;

    float s = ws[REC_OFF + (size_t)t * REC_STRIDE]
            + ws[REC_OFF + (size_t)(t + 1024) * REC_STRIDE];
    #pragma unroll
    for (int off = 32; off > 0; off >>= 1) s += __shfl_down(s, off, 64);
    if ((t & 63) == 0) sm[t >> 6] = s;
    __syncthreads();
    if (t == 0) {
        float tot = 0.f;
        #pragma unroll
        for (int i = 0; i < 16; ++i) tot += sm[i];
        smean = tot * (1.0f / (float)N_NODES);
    }
    __syncthreads();
    const float mean = smean;

    const int g = t;                       // 1024 graphs, 1024 threads
    const int* ibase = (const int*)(ws + IBASE_OFF);
    const float* extra = ws + EXTRA_OFF;

    float qx = extra[g * 6 + 0], qy = extra[g * 6 + 1], qz = extra[g * 6 + 2];
    float rx = extra[g * 6 + 3], ry = extra[g * 6 + 4], rz = extra[g * 6 + 5];

    // last block b with ibase[b] <= g
    int lo = 0, hi = NBLOCKS - 1, B = -1;
    while (lo <= hi) {
        int mid = (lo + hi) >> 1;
        if (ibase[mid] <= g) { B = mid; lo = mid + 1; } else hi = mid - 1;
    }
    // walk left; block b's slot (g - ibase[b]) holds id g's partial (zero if absent)
    for (int b = B; b >= 0; --b) {
        int sl = g - ibase[b];
        if (sl >= NSLOT) break;            // earlier blocks spilled id g to extra[]
        const float* p = ws + REC_OFF + (size_t)b * REC_STRIDE + 8 + sl * 6;
        qx += p[0]; qy += p[1]; qz += p[2];
        rx += p[3]; ry += p[4]; rz += p[5];
    }
    out[g * 3 + 0] = fmaf(-mean, rx, qx);
    out[g * 3 + 1] = fmaf(-mean, ry, qy);
    out[g * 3 + 2] = fmaf(-mean, rz, qz);
}

// ---------------- fallback path (round-1 code, known correct) ----------------

__global__ void sum_q_kernel(const float* __restrict__ q, float* __restrict__ ws, int n4) {
    int tid = blockIdx.x * blockDim.x + threadIdx.x;
    int stride = gridDim.x * blockDim.x;
    const float4* q4 = (const float4*)q;
    float s = 0.f;
    for (int i = tid; i < n4; i += stride) {
        float4 v = q4[i];
        s += (v.x + v.y) + (v.z + v.w);
    }
    for (int off = 32; off > 0; off >>= 1) s += __shfl_down(s, off, 64);
    __shared__ float smem[4];
    int lane = threadIdx.x & 63, wave = threadIdx.x >> 6;
    if (lane == 0) smem[wave] = s;
    __syncthreads();
    if (threadIdx.x == 0) atomicAdd(ws, (smem[0] + smem[1]) + (smem[2] + smem[3]));
}

__global__ void pol_atomic_kernel(const float* __restrict__ pos,
                                  const float* __restrict__ q,
                                  const int*   __restrict__ batch,
                                  const float* __restrict__ ws,
                                  float* __restrict__ out, int n) {
    const float mean = ws[0] * (1.0f / (float)N_NODES);
    int tid = blockIdx.x * blockDim.x + threadIdx.x;
    int stride = gridDim.x * blockDim.x;
    int n4 = n >> 2;
    const float4* q4 = (const float4*)q;
    const int4*   b4 = (const int4*)batch;
    const float4* p4 = (const float4*)pos;

    for (int i = tid; i < n4; i += stride) {
        float4 qv = q4[i];
        int4   bv = b4[i];
        float4 p0 = p4[3 * i + 0];
        float4 p1 = p4[3 * i + 1];
        float4 p2 = p4[3 * i + 2];
        float qs[4] = {qv.x - mean, qv.y - mean, qv.z - mean, qv.w - mean};
        int  ids[4] = {bv.x, bv.y, bv.z, bv.w};
        float px[4] = {p0.x, p0.w, p1.z, p2.y};
        float py[4] = {p0.y, p1.x, p1.w, p2.z};
        float pz[4] = {p0.z, p1.y, p2.x, p2.w};
        int cur = ids[0];
        float sx = 0.f, sy = 0.f, sz = 0.f;
        #pragma unroll
        for (int j = 0; j < 4; ++j) {
            if (ids[j] != cur) {
                atomicAdd(&out[cur * 3 + 0], sx);
                atomicAdd(&out[cur * 3 + 1], sy);
                atomicAdd(&out[cur * 3 + 2], sz);
                sx = sy = sz = 0.f;
                cur = ids[j];
            }
            sx = fmaf(qs[j], px[j], sx);
            sy = fmaf(qs[j], py[j], sy);
            sz = fmaf(qs[j], pz[j], sz);
        }
        int first = __shfl(cur, 0, 64);
        bool uniform = __all(cur == first);
        if (uniform) {
            for (int off = 32; off > 0; off >>= 1) {
                sx += __shfl_down(sx, off, 64);
                sy += __shfl_down(sy, off, 64);
                sz += __shfl_down(sz, off, 64);
            }
            if ((threadIdx.x & 63) == 0) {
                atomicAdd(&out[cur * 3 + 0], sx);
                atomicAdd(&out[cur * 3 + 1], sy);
                atomicAdd(&out[cur * 3 + 2], sz);
            }
        } else {
            atomicAdd(&out[cur * 3 + 0], sx);
            atomicAdd(&out[cur * 3 + 1], sy);
            atomicAdd(&out[cur * 3 + 2], sz);
        }
    }
}

extern "C" void kernel_launch(void* const* d_in, const int* in_sizes, int n_in,
                              void* d_out, int out_size, void* d_ws, size_t ws_size,
                              hipStream_t stream) {
    const float* pos   = (const float*)d_in[0];
    const float* q     = (const float*)d_in[1];
    const int*   batch = (const int*)d_in[2];
    float* out = (float*)d_out;
    float* ws  = (float*)d_ws;
    int n = in_sizes[1];

    if (ws_size >= (size_t)WS_FLOATS * sizeof(float)) {
        hipMemsetAsync(ws + EXTRA_OFF, 0, (size_t)NUM_GRAPHS * 6 * sizeof(float), stream);
        pol_main<<<NBLOCKS, BLK, 0, stream>>>((const float4*)pos, (const float4*)q,
                                              (const int4*)batch, batch, ws);
        finalize_kernel<<<1, 1024, 0, stream>>>(ws, out);
    } else {
        hipMemsetAsync(d_out, 0, (size_t)out_size * sizeof(float), stream);
        hipMemsetAsync(d_ws, 0, sizeof(float), stream);
        sum_q_kernel<<<4096, BLK, 0, stream>>>(q, ws, n >> 2);
        pol_atomic_kernel<<<8192, BLK, 0, stream>>>(pos, q, batch, ws, out, n);
    }
}

// Round 5
// 204.579 us; speedup vs baseline: 1.8082x; 1.0277x over previous
//
#include <hip/hip_runtime.h>

// pol[g] = sum_{i in g} (q_i - mean(q)) * r_i = (sum_g q r) - mean * (sum_g r)
// pol_main: 2048 blocks x 256 thr, 16 nodes/thread. Sorted batch + big segments
// => block spans <=2 graphs: thread0 finds the one split point by binary search,
// inner loop is a compare-select between two accumulator sets (NO per-node batch
// reads, NO id state machine). Loads explicitly batched (16 in flight) for MLP.
// Record format + finalize identical to round-4 (proven).

#define N_NODES         8388608
#define NUM_GRAPHS      1024
#define BLK             256
#define NODES_PER_BLOCK 4096
#define NBLOCKS         (N_NODES / NODES_PER_BLOCK)     // 2048
#define ITER            4                                // ITER*BLK*4 == NODES_PER_BLOCK
#define NSLOT           4

// ws layout (float offsets)
#define IBASE_OFF       16                               // int ibase[NBLOCKS]
#define REC_OFF         2064                             // rec[NBLOCKS][32]: [0]=qsum, [8..31]=slots
#define REC_STRIDE      32
#define EXTRA_OFF       (REC_OFF + NBLOCKS * REC_STRIDE) // 67600
#define WS_FLOATS       (EXTRA_OFF + NUM_GRAPHS * 6)     // 73744 floats = 294976 B

__global__ __launch_bounds__(BLK) void pol_main(const float4* __restrict__ p4,
                                                const float4* __restrict__ q4,
                                                const int*    __restrict__ batch,
                                                float* __restrict__ ws) {
    __shared__ float sslot[NSLOT * 6];
    __shared__ float sqsum;
    __shared__ int   sh_i0, sh_i1, sh_split;

    const int t = threadIdx.x;
    const int b = blockIdx.x;
    float* extra = ws + EXTRA_OFF;

    const int s = b * NODES_PER_BLOCK;
    const int e = s + NODES_PER_BLOCK;

    if (t < NSLOT * 6) sslot[t] = 0.f;
    if (t == 0) {
        sqsum = 0.f;
        int i0 = batch[s];
        int i1 = batch[e - 1];
        int split = e;
        if (i1 != i0) {   // first index in (s,e) with batch[] > i0
            int lo = s + 1, hi = e - 1;
            while (lo < hi) {
                int mid = (lo + hi) >> 1;
                if (batch[mid] > i0) hi = mid; else lo = mid + 1;
            }
            split = lo;
        }
        sh_i0 = i0; sh_i1 = i1; sh_split = split;
    }
    __syncthreads();
    const int i0 = sh_i0, i1 = sh_i1, split = sh_split;
    const bool general = (i1 > i0 + 1);   // >=3 graphs in block: impossible here

    // ---- batched loads: 16 independent vector loads in flight ----
    float4 Q[ITER], P0[ITER], P1[ITER], P2[ITER];
    const int blk_v4 = b * (NODES_PER_BLOCK / 4);
    #pragma unroll
    for (int j = 0; j < ITER; ++j) {
        int vi = blk_v4 + j * BLK + t;
        Q[j]  = q4[vi];
        P0[j] = p4[3 * vi + 0];
        P1[j] = p4[3 * vi + 1];
        P2[j] = p4[3 * vi + 2];
    }

    float aqx = 0, aqy = 0, aqz = 0, arx = 0, ary = 0, arz = 0;
    float bqx = 0, bqy = 0, bqz = 0, brx = 0, bry = 0, brz = 0;
    float qsum = 0.f;

    if (!general) {
        #pragma unroll
        for (int j = 0; j < ITER; ++j) {
            int gidx = (blk_v4 + j * BLK + t) * 4;   // absolute node index of element 0
            float qs[4] = {Q[j].x, Q[j].y, Q[j].z, Q[j].w};
            float px[4] = {P0[j].x, P0[j].w, P1[j].z, P2[j].y};
            float py[4] = {P0[j].y, P1[j].x, P1[j].w, P2[j].z};
            float pz[4] = {P0[j].z, P1[j].y, P2[j].x, P2[j].w};
            qsum += (qs[0] + qs[1]) + (qs[2] + qs[3]);
            #pragma unroll
            for (int k = 0; k < 4; ++k) {
                if (gidx + k < split) {
                    aqx = fmaf(qs[k], px[k], aqx); aqy = fmaf(qs[k], py[k], aqy);
                    aqz = fmaf(qs[k], pz[k], aqz);
                    arx += px[k]; ary += py[k]; arz += pz[k];
                } else {
                    bqx = fmaf(qs[k], px[k], bqx); bqy = fmaf(qs[k], py[k], bqy);
                    bqz = fmaf(qs[k], pz[k], bqz);
                    brx += px[k]; bry += py[k]; brz += pz[k];
                }
            }
        }
    } else {  // never for this input: per-node id lookup + global atomics (correct)
        #pragma unroll
        for (int j = 0; j < ITER; ++j) {
            int gidx = (blk_v4 + j * BLK + t) * 4;
            float qs[4] = {Q[j].x, Q[j].y, Q[j].z, Q[j].w};
            float px[4] = {P0[j].x, P0[j].w, P1[j].z, P2[j].y};
            float py[4] = {P0[j].y, P1[j].x, P1[j].w, P2[j].z};
            float pz[4] = {P0[j].z, P1[j].y, P2[j].x, P2[j].w};
            for (int k = 0; k < 4; ++k) {
                int id = batch[gidx + k];
                float qv = qs[k];
                qsum += qv;
                atomicAdd(&extra[id * 6 + 0], qv * px[k]);
                atomicAdd(&extra[id * 6 + 1], qv * py[k]);
                atomicAdd(&extra[id * 6 + 2], qv * pz[k]);
                atomicAdd(&extra[id * 6 + 3], px[k]);
                atomicAdd(&extra[id * 6 + 4], py[k]);
                atomicAdd(&extra[id * 6 + 5], pz[k]);
            }
        }
    }

    // block qsum: wave butterfly + one LDS atomic per wave
    #pragma unroll
    for (int off = 32; off > 0; off >>= 1) qsum += __shfl_down(qsum, off, 64);
    if ((t & 63) == 0) atomicAdd(&sqsum, qsum);

    if (!general) {
        // segment A -> slot 0 (graph i0); lanes with no A nodes contribute zeros
        #pragma unroll
        for (int off = 32; off > 0; off >>= 1) {
            aqx += __shfl_down(aqx, off, 64); aqy += __shfl_down(aqy, off, 64);
            aqz += __shfl_down(aqz, off, 64); arx += __shfl_down(arx, off, 64);
            ary += __shfl_down(ary, off, 64); arz += __shfl_down(arz, off, 64);
        }
        if ((t & 63) == 0) {
            atomicAdd(&sslot[0], aqx); atomicAdd(&sslot[1], aqy);
            atomicAdd(&sslot[2], aqz); atomicAdd(&sslot[3], arx);
            atomicAdd(&sslot[4], ary); atomicAdd(&sslot[5], arz);
        }
        if (split < e) {   // segment B -> slot (i1-i0) == 1
            #pragma unroll
            for (int off = 32; off > 0; off >>= 1) {
                bqx += __shfl_down(bqx, off, 64); bqy += __shfl_down(bqy, off, 64);
                bqz += __shfl_down(bqz, off, 64); brx += __shfl_down(brx, off, 64);
                bry += __shfl_down(bry, off, 64); brz += __shfl_down(brz, off, 64);
            }
            if ((t & 63) == 0) {
                int sl = i1 - i0;   // == 1
                atomicAdd(&sslot[sl * 6 + 0], bqx); atomicAdd(&sslot[sl * 6 + 1], bqy);
                atomicAdd(&sslot[sl * 6 + 2], bqz); atomicAdd(&sslot[sl * 6 + 3], brx);
                atomicAdd(&sslot[sl * 6 + 4], bry); atomicAdd(&sslot[sl * 6 + 5], brz);
            }
        }
    }
    __syncthreads();

    float* rec = ws + REC_OFF + (size_t)b * REC_STRIDE;
    if (t == 0) {
        rec[0] = sqsum;
        ((int*)(ws + IBASE_OFF))[b] = i0;
    }
    if (t < NSLOT * 6) rec[8 + t] = sslot[t];
}

// Single block, 1024 threads: mean from 2048 block qsums, then per-graph gather
// via binary search over sorted block base ids (round-3/4 proven logic).
__global__ __launch_bounds__(1024) void finalize_kernel(const float* __restrict__ ws,
                                                        float* __restrict__ out) {
    __shared__ float sm[16];
    __shared__ float smean;
    const int t = threadIdx.x;

    float s = ws[REC_OFF + (size_t)t * REC_STRIDE]
            + ws[REC_OFF + (size_t)(t + 1024) * REC_STRIDE];
    #pragma unroll
    for (int off = 32; off > 0; off >>= 1) s += __shfl_down(s, off, 64);
    if ((t & 63) == 0) sm[t >> 6] = s;
    __syncthreads();
    if (t == 0) {
        float tot = 0.f;
        #pragma unroll
        for (int i = 0; i < 16; ++i) tot += sm[i];
        smean = tot * (1.0f / (float)N_NODES);
    }
    __syncthreads();
    const float mean = smean;

    const int g = t;
    const int* ibase = (const int*)(ws + IBASE_OFF);
    const float* extra = ws + EXTRA_OFF;

    float qx = extra[g * 6 + 0], qy = extra[g * 6 + 1], qz = extra[g * 6 + 2];
    float rx = extra[g * 6 + 3], ry = extra[g * 6 + 4], rz = extra[g * 6 + 5];

    int lo = 0, hi = NBLOCKS - 1, B = -1;
    while (lo <= hi) {
        int mid = (lo + hi) >> 1;
        if (ibase[mid] <= g) { B = mid; lo = mid + 1; } else hi = mid - 1;
    }
    for (int b = B; b >= 0; --b) {
        int sl = g - ibase[b];
        if (sl >= NSLOT) break;
        const float* p = ws + REC_OFF + (size_t)b * REC_STRIDE + 8 + sl * 6;
        qx += p[0]; qy += p[1]; qz += p[2];
        rx += p[3]; ry += p[4]; rz += p[5];
    }
    out[g * 3 + 0] = fmaf(-mean, rx, qx);
    out[g * 3 + 1] = fmaf(-mean, ry, qy);
    out[g * 3 + 2] = fmaf(-mean, rz, qz);
}

// ---------------- fallback path (round-1 code, known correct) ----------------

__global__ void sum_q_kernel(const float* __restrict__ q, float* __restrict__ ws, int n4) {
    int tid = blockIdx.x * blockDim.x + threadIdx.x;
    int stride = gridDim.x * blockDim.x;
    const float4* q4 = (const float4*)q;
    float s = 0.f;
    for (int i = tid; i < n4; i += stride) {
        float4 v = q4[i];
        s += (v.x + v.y) + (v.z + v.w);
    }
    for (int off = 32; off > 0; off >>= 1) s += __shfl_down(s, off, 64);
    __shared__ float smem[4];
    int lane = threadIdx.x & 63, wave = threadIdx.x >> 6;
    if (lane == 0) smem[wave] = s;
    __syncthreads();
    if (threadIdx.x == 0) atomicAdd(ws, (smem[0] + smem[1]) + (smem[2] + smem[3]));
}

__global__ void pol_atomic_kernel(const float* __restrict__ pos,
                                  const float* __restrict__ q,
                                  const int*   __restrict__ batch,
                                  const float* __restrict__ ws,
                                  float* __restrict__ out, int n) {
    const float mean = ws[0] * (1.0f / (float)N_NODES);
    int tid = blockIdx.x * blockDim.x + threadIdx.x;
    int stride = gridDim.x * blockDim.x;
    int n4 = n >> 2;
    const float4* q4 = (const float4*)q;
    const int4*   b4 = (const int4*)batch;
    const float4* p4 = (const float4*)pos;

    for (int i = tid; i < n4; i += stride) {
        float4 qv = q4[i];
        int4   bv = b4[i];
        float4 p0 = p4[3 * i + 0];
        float4 p1 = p4[3 * i + 1];
        float4 p2 = p4[3 * i + 2];
        float qs[4] = {qv.x - mean, qv.y - mean, qv.z - mean, qv.w - mean};
        int  ids[4] = {bv.x, bv.y, bv.z, bv.w};
        float px[4] = {p0.x, p0.w, p1.z, p2.y};
        float py[4] = {p0.y, p1.x, p1.w, p2.z};
        float pz[4] = {p0.z, p1.y, p2.x, p2.w};
        int cur = ids[0];
        float sx = 0.f, sy = 0.f, sz = 0.f;
        #pragma unroll
        for (int j = 0; j < 4; ++j) {
            if (ids[j] != cur) {
                atomicAdd(&out[cur * 3 + 0], sx);
                atomicAdd(&out[cur * 3 + 1], sy);
                atomicAdd(&out[cur * 3 + 2], sz);
                sx = sy = sz = 0.f;
                cur = ids[j];
            }
            sx = fmaf(qs[j], px[j], sx);
            sy = fmaf(qs[j], py[j], sy);
            sz = fmaf(qs[j], pz[j], sz);
        }
        int first = __shfl(cur, 0, 64);
        bool uniform = __all(cur == first);
        if (uniform) {
            for (int off = 32; off > 0; off >>= 1) {
                sx += __shfl_down(sx, off, 64);
                sy += __shfl_down(sy, off, 64);
                sz += __shfl_down(sz, off, 64);
            }
            if ((threadIdx.x & 63) == 0) {
                atomicAdd(&out[cur * 3 + 0], sx);
                atomicAdd(&out[cur * 3 + 1], sy);
                atomicAdd(&out[cur * 3 + 2], sz);
            }
        } else {
            atomicAdd(&out[cur * 3 + 0], sx);
            atomicAdd(&out[cur * 3 + 1], sy);
            atomicAdd(&out[cur * 3 + 2], sz);
        }
    }
}

extern "C" void kernel_launch(void* const* d_in, const int* in_sizes, int n_in,
                              void* d_out, int out_size, void* d_ws, size_t ws_size,
                              hipStream_t stream) {
    const float* pos   = (const float*)d_in[0];
    const float* q     = (const float*)d_in[1];
    const int*   batch = (const int*)d_in[2];
    float* out = (float*)d_out;
    float* ws  = (float*)d_ws;
    int n = in_sizes[1];

    if (ws_size >= (size_t)WS_FLOATS * sizeof(float)) {
        hipMemsetAsync(ws + EXTRA_OFF, 0, (size_t)NUM_GRAPHS * 6 * sizeof(float), stream);
        pol_main<<<NBLOCKS, BLK, 0, stream>>>((const float4*)pos, (const float4*)q,
                                              batch, ws);
        finalize_kernel<<<1, 1024, 0, stream>>>(ws, out);
    } else {
        hipMemsetAsync(d_out, 0, (size_t)out_size * sizeof(float), stream);
        hipMemsetAsync(d_ws, 0, sizeof(float), stream);
        sum_q_kernel<<<4096, BLK, 0, stream>>>(q, ws, n >> 2);
        pol_atomic_kernel<<<8192, BLK, 0, stream>>>(pos, q, batch, ws, out, n);
    }
}

// Round 6
// 204.521 us; speedup vs baseline: 1.8087x; 1.0003x over previous
//
#include <hip/hip_runtime.h>

// pol[g] = sum_{i in g} (q_i - mean(q)) * r_i = (sum_g q r) - mean * (sum_g r)
// split_kernel: one thread per main block does the block's segment-split binary
//   search (all 2048 searches latency-overlapped), writes {i0,i1,split} + ibase,
//   and zeroes the extra[] overflow region (replaces the memset dispatch).
// pol_main: 2048 blocks x 256 thr, 16 nodes/thread. Reads precomputed split,
//   issues 16 bulk vector loads with nothing ahead of them, compare-select
//   accumulation, wave butterflies, LDS-slot flush, plain-store records.
// finalize: mean from block qsums + per-graph gather via binary search (proven).

#define N_NODES         8388608
#define NUM_GRAPHS      1024
#define BLK             256
#define NODES_PER_BLOCK 4096
#define NBLOCKS         (N_NODES / NODES_PER_BLOCK)     // 2048
#define ITER            4                                // ITER*BLK*4 == NODES_PER_BLOCK
#define NSLOT           4

// ws layout (float offsets)
#define IBASE_OFF       16                               // int ibase[NBLOCKS]
#define SPLIT_OFF       2064                             // int4 split[NBLOCKS]
#define REC_OFF         10256                            // rec[NBLOCKS][32]: [0]=qsum, [8..31]=slots
#define REC_STRIDE      32
#define EXTRA_OFF       (REC_OFF + NBLOCKS * REC_STRIDE) // 75792
#define WS_FLOATS       (EXTRA_OFF + NUM_GRAPHS * 6)     // 81936 floats = 327744 B

__global__ __launch_bounds__(BLK) void split_kernel(const int* __restrict__ batch,
                                                    float* __restrict__ ws) {
    int b = blockIdx.x * BLK + threadIdx.x;   // 0..NBLOCKS-1
    if (b >= NBLOCKS) return;

    // zero extra[] : 6144 floats, 3 per thread
    float* extra = ws + EXTRA_OFF;
    extra[b * 3 + 0] = 0.f; extra[b * 3 + 1] = 0.f; extra[b * 3 + 2] = 0.f;

    const int s = b * NODES_PER_BLOCK;
    const int e = s + NODES_PER_BLOCK;
    int i0 = batch[s];
    int i1 = batch[e - 1];
    int split = e;
    if (i1 != i0) {   // first index in (s,e) with batch[] > i0
        int lo = s + 1, hi = e - 1;
        while (lo < hi) {
            int mid = (lo + hi) >> 1;
            if (batch[mid] > i0) hi = mid; else lo = mid + 1;
        }
        split = lo;
    }
    ((int4*)(ws + SPLIT_OFF))[b] = make_int4(i0, i1, split, 0);
    ((int*)(ws + IBASE_OFF))[b] = i0;
}

__global__ __launch_bounds__(BLK) void pol_main(const float4* __restrict__ p4,
                                                const float4* __restrict__ q4,
                                                const int*    __restrict__ batch,
                                                float* __restrict__ ws) {
    __shared__ float sslot[NSLOT * 6];
    __shared__ float sqsum;

    const int t = threadIdx.x;
    const int b = blockIdx.x;
    float* extra = ws + EXTRA_OFF;

    const int e = (b + 1) * NODES_PER_BLOCK;
    const int4 si = ((const int4*)(ws + SPLIT_OFF))[b];   // {i0, i1, split}
    const int i0 = si.x, i1 = si.y, split = si.z;
    const bool general = (i1 > i0 + 1);   // >=3 graphs in block: impossible here

    if (t < NSLOT * 6) sslot[t] = 0.f;
    if (t == 0) sqsum = 0.f;
    __syncthreads();          // LDS-only; nothing big in vmem flight yet

    // ---- bulk loads: 16 independent vector loads in flight, nothing ahead ----
    float4 Q[ITER], P0[ITER], P1[ITER], P2[ITER];
    const int blk_v4 = b * (NODES_PER_BLOCK / 4);
    #pragma unroll
    for (int j = 0; j < ITER; ++j) {
        int vi = blk_v4 + j * BLK + t;
        Q[j]  = q4[vi];
        P0[j] = p4[3 * vi + 0];
        P1[j] = p4[3 * vi + 1];
        P2[j] = p4[3 * vi + 2];
    }

    float aqx = 0, aqy = 0, aqz = 0, arx = 0, ary = 0, arz = 0;
    float bqx = 0, bqy = 0, bqz = 0, brx = 0, bry = 0, brz = 0;
    float qsum = 0.f;

    if (!general) {
        #pragma unroll
        for (int j = 0; j < ITER; ++j) {
            int gidx = (blk_v4 + j * BLK + t) * 4;   // absolute node index of element 0
            float qs[4] = {Q[j].x, Q[j].y, Q[j].z, Q[j].w};
            float px[4] = {P0[j].x, P0[j].w, P1[j].z, P2[j].y};
            float py[4] = {P0[j].y, P1[j].x, P1[j].w, P2[j].z};
            float pz[4] = {P0[j].z, P1[j].y, P2[j].x, P2[j].w};
            qsum += (qs[0] + qs[1]) + (qs[2] + qs[3]);
            #pragma unroll
            for (int k = 0; k < 4; ++k) {
                if (gidx + k < split) {
                    aqx = fmaf(qs[k], px[k], aqx); aqy = fmaf(qs[k], py[k], aqy);
                    aqz = fmaf(qs[k], pz[k], aqz);
                    arx += px[k]; ary += py[k]; arz += pz[k];
                } else {
                    bqx = fmaf(qs[k], px[k], bqx); bqy = fmaf(qs[k], py[k], bqy);
                    bqz = fmaf(qs[k], pz[k], bqz);
                    brx += px[k]; bry += py[k]; brz += pz[k];
                }
            }
        }
    } else {  // never for this input: per-node id lookup + global atomics (correct)
        #pragma unroll
        for (int j = 0; j < ITER; ++j) {
            int gidx = (blk_v4 + j * BLK + t) * 4;
            float qs[4] = {Q[j].x, Q[j].y, Q[j].z, Q[j].w};
            float px[4] = {P0[j].x, P0[j].w, P1[j].z, P2[j].y};
            float py[4] = {P0[j].y, P1[j].x, P1[j].w, P2[j].z};
            float pz[4] = {P0[j].z, P1[j].y, P2[j].x, P2[j].w};
            for (int k = 0; k < 4; ++k) {
                int id = batch[gidx + k];
                float qv = qs[k];
                qsum += qv;
                atomicAdd(&extra[id * 6 + 0], qv * px[k]);
                atomicAdd(&extra[id * 6 + 1], qv * py[k]);
                atomicAdd(&extra[id * 6 + 2], qv * pz[k]);
                atomicAdd(&extra[id * 6 + 3], px[k]);
                atomicAdd(&extra[id * 6 + 4], py[k]);
                atomicAdd(&extra[id * 6 + 5], pz[k]);
            }
        }
    }

    // block qsum: wave butterfly + one LDS atomic per wave
    #pragma unroll
    for (int off = 32; off > 0; off >>= 1) qsum += __shfl_down(qsum, off, 64);
    if ((t & 63) == 0) atomicAdd(&sqsum, qsum);

    if (!general) {
        // segment A -> slot 0 (graph i0)
        #pragma unroll
        for (int off = 32; off > 0; off >>= 1) {
            aqx += __shfl_down(aqx, off, 64); aqy += __shfl_down(aqy, off, 64);
            aqz += __shfl_down(aqz, off, 64); arx += __shfl_down(arx, off, 64);
            ary += __shfl_down(ary, off, 64); arz += __shfl_down(arz, off, 64);
        }
        if ((t & 63) == 0) {
            atomicAdd(&sslot[0], aqx); atomicAdd(&sslot[1], aqy);
            atomicAdd(&sslot[2], aqz); atomicAdd(&sslot[3], arx);
            atomicAdd(&sslot[4], ary); atomicAdd(&sslot[5], arz);
        }
        if (split < e) {   // segment B -> slot (i1-i0) == 1
            #pragma unroll
            for (int off = 32; off > 0; off >>= 1) {
                bqx += __shfl_down(bqx, off, 64); bqy += __shfl_down(bqy, off, 64);
                bqz += __shfl_down(bqz, off, 64); brx += __shfl_down(brx, off, 64);
                bry += __shfl_down(bry, off, 64); brz += __shfl_down(brz, off, 64);
            }
            if ((t & 63) == 0) {
                int sl = i1 - i0;   // == 1
                atomicAdd(&sslot[sl * 6 + 0], bqx); atomicAdd(&sslot[sl * 6 + 1], bqy);
                atomicAdd(&sslot[sl * 6 + 2], bqz); atomicAdd(&sslot[sl * 6 + 3], brx);
                atomicAdd(&sslot[sl * 6 + 4], bry); atomicAdd(&sslot[sl * 6 + 5], brz);
            }
        }
    }
    __syncthreads();

    float* rec = ws + REC_OFF + (size_t)b * REC_STRIDE;
    if (t == 0) rec[0] = sqsum;
    if (t < NSLOT * 6) rec[8 + t] = sslot[t];
}

// Single block, 1024 threads: mean from 2048 block qsums, then per-graph gather
// via binary search over sorted block base ids (round-3/4/5 proven logic).
__global__ __launch_bounds__(1024) void finalize_kernel(const float* __restrict__ ws,
                                                        float* __restrict__ out) {
    __shared__ float sm[16];
    __shared__ float smean;
    const int t = threadIdx.x;

    float s = ws[REC_OFF + (size_t)t * REC_STRIDE]
            + ws[REC_OFF + (size_t)(t + 1024) * REC_STRIDE];
    #pragma unroll
    for (int off = 32; off > 0; off >>= 1) s += __shfl_down(s, off, 64);
    if ((t & 63) == 0) sm[t >> 6] = s;
    __syncthreads();
    if (t == 0) {
        float tot = 0.f;
        #pragma unroll
        for (int i = 0; i < 16; ++i) tot += sm[i];
        smean = tot * (1.0f / (float)N_NODES);
    }
    __syncthreads();
    const float mean = smean;

    const int g = t;
    const int* ibase = (const int*)(ws + IBASE_OFF);
    const float* extra = ws + EXTRA_OFF;

    float qx = extra[g * 6 + 0], qy = extra[g * 6 + 1], qz = extra[g * 6 + 2];
    float rx = extra[g * 6 + 3], ry = extra[g * 6 + 4], rz = extra[g * 6 + 5];

    int lo = 0, hi = NBLOCKS - 1, B = -1;
    while (lo <= hi) {
        int mid = (lo + hi) >> 1;
        if (ibase[mid] <= g) { B = mid; lo = mid + 1; } else hi = mid - 1;
    }
    for (int b = B; b >= 0; --b) {
        int sl = g - ibase[b];
        if (sl >= NSLOT) break;
        const float* p = ws + REC_OFF + (size_t)b * REC_STRIDE + 8 + sl * 6;
        qx += p[0]; qy += p[1]; qz += p[2];
        rx += p[3]; ry += p[4]; rz += p[5];
    }
    out[g * 3 + 0] = fmaf(-mean, rx, qx);
    out[g * 3 + 1] = fmaf(-mean, ry, qy);
    out[g * 3 + 2] = fmaf(-mean, rz, qz);
}

// ---------------- fallback path (round-1 code, known correct) ----------------

__global__ void sum_q_kernel(const float* __restrict__ q, float* __restrict__ ws, int n4) {
    int tid = blockIdx.x * blockDim.x + threadIdx.x;
    int stride = gridDim.x * blockDim.x;
    const float4* q4 = (const float4*)q;
    float s = 0.f;
    for (int i = tid; i < n4; i += stride) {
        float4 v = q4[i];
        s += (v.x + v.y) + (v.z + v.w);
    }
    for (int off = 32; off > 0; off >>= 1) s += __shfl_down(s, off, 64);
    __shared__ float smem[4];
    int lane = threadIdx.x & 63, wave = threadIdx.x >> 6;
    if (lane == 0) smem[wave] = s;
    __syncthreads();
    if (threadIdx.x == 0) atomicAdd(ws, (smem[0] + smem[1]) + (smem[2] + smem[3]));
}

__global__ void pol_atomic_kernel(const float* __restrict__ pos,
                                  const float* __restrict__ q,
                                  const int*   __restrict__ batch,
                                  const float* __restrict__ ws,
                                  float* __restrict__ out, int n) {
    const float mean = ws[0] * (1.0f / (float)N_NODES);
    int tid = blockIdx.x * blockDim.x + threadIdx.x;
    int stride = gridDim.x * blockDim.x;
    int n4 = n >> 2;
    const float4* q4 = (const float4*)q;
    const int4*   b4 = (const int4*)batch;
    const float4* p4 = (const float4*)pos;

    for (int i = tid; i < n4; i += stride) {
        float4 qv = q4[i];
        int4   bv = b4[i];
        float4 p0 = p4[3 * i + 0];
        float4 p1 = p4[3 * i + 1];
        float4 p2 = p4[3 * i + 2];
        float qs[4] = {qv.x - mean, qv.y - mean, qv.z - mean, qv.w - mean};
        int  ids[4] = {bv.x, bv.y, bv.z, bv.w};
        float px[4] = {p0.x, p0.w, p1.z, p2.y};
        float py[4] = {p0.y, p1.x, p1.w, p2.z};
        float pz[4] = {p0.z, p1.y, p2.x, p2.w};
        int cur = ids[0];
        float sx = 0.f, sy = 0.f, sz = 0.f;
        #pragma unroll
        for (int j = 0; j < 4; ++j) {
            if (ids[j] != cur) {
                atomicAdd(&out[cur * 3 + 0], sx);
                atomicAdd(&out[cur * 3 + 1], sy);
                atomicAdd(&out[cur * 3 + 2], sz);
                sx = sy = sz = 0.f;
                cur = ids[j];
            }
            sx = fmaf(qs[j], px[j], sx);
            sy = fmaf(qs[j], py[j], sy);
            sz = fmaf(qs[j], pz[j], sz);
        }
        int first = __shfl(cur, 0, 64);
        bool uniform = __all(cur == first);
        if (uniform) {
            for (int off = 32; off > 0; off >>= 1) {
                sx += __shfl_down(sx, off, 64);
                sy += __shfl_down(sy, off, 64);
                sz += __shfl_down(sz, off, 64);
            }
            if ((threadIdx.x & 63) == 0) {
                atomicAdd(&out[cur * 3 + 0], sx);
                atomicAdd(&out[cur * 3 + 1], sy);
                atomicAdd(&out[cur * 3 + 2], sz);
            }
        } else {
            atomicAdd(&out[cur * 3 + 0], sx);
            atomicAdd(&out[cur * 3 + 1], sy);
            atomicAdd(&out[cur * 3 + 2], sz);
        }
    }
}

extern "C" void kernel_launch(void* const* d_in, const int* in_sizes, int n_in,
                              void* d_out, int out_size, void* d_ws, size_t ws_size,
                              hipStream_t stream) {
    const float* pos   = (const float*)d_in[0];
    const float* q     = (const float*)d_in[1];
    const int*   batch = (const int*)d_in[2];
    float* out = (float*)d_out;
    float* ws  = (float*)d_ws;
    int n = in_sizes[1];

    if (ws_size >= (size_t)WS_FLOATS * sizeof(float)) {
        split_kernel<<<NBLOCKS / BLK, BLK, 0, stream>>>(batch, ws);   // 8 blocks
        pol_main<<<NBLOCKS, BLK, 0, stream>>>((const float4*)pos, (const float4*)q,
                                              batch, ws);
        finalize_kernel<<<1, 1024, 0, stream>>>(ws, out);
    } else {
        hipMemsetAsync(d_out, 0, (size_t)out_size * sizeof(float), stream);
        hipMemsetAsync(d_ws, 0, sizeof(float), stream);
        sum_q_kernel<<<4096, BLK, 0, stream>>>(q, ws, n >> 2);
        pol_atomic_kernel<<<8192, BLK, 0, stream>>>(pos, q, batch, ws, out, n);
    }
}